// Round 2
// baseline (528.120 us; speedup 1.0000x reference)
//
#include <hip/hip_runtime.h>

typedef float f32x4 __attribute__((ext_vector_type(4)));
typedef unsigned int u32x4 __attribute__((ext_vector_type(4)));
typedef _Float16 f16x8 __attribute__((ext_vector_type(8)));
typedef unsigned short u16;

// ---- constants ----
#define NWIN 8192
#define NTOK 64
#define DIM 128
#define HEADS 4
#define HD 32
#define MAX_LOG_SCALE 4.605170185988091f  // log(100)

// LDS offsets (bytes). 80 KB total -> 2 blocks/CU.
#define LDS_X1 0        // [64][128] f16, also P region (4 heads x 8KB) in phase 2
#define LDS_X2 16384
#define LDS_Q  32768    // [64][128] f16, also O region in phase 2/3
#define LDS_K  49152
#define LDS_VT 65536    // [128][64] f16 (v transposed)
#define LDS_BYTES 81920

// Builtin MFMA (hazard recognizer + scheduler handle MAI wait states; inline
// asm MFMA left the MFMA->VALU RAW hazard unprotected -> round-1 corruption).
__device__ __forceinline__ void mfma16(f32x4& acc, u32x4 a, u32x4 b) {
  acc = __builtin_amdgcn_mfma_f32_16x16x32_f16(
      __builtin_bit_cast(f16x8, a), __builtin_bit_cast(f16x8, b), acc, 0, 0, 0);
}

__device__ __forceinline__ u16 f2h(float f) {
  return __builtin_bit_cast(u16, (_Float16)f);
}

// XOR swizzle: spreads row-major [r][128]f16 (256B rows) / [r][64]f16 (128B rows)
// column reads across banks. 16B-granule bijective within each 8-row stripe.
__device__ __forceinline__ int swz(int row, int colbyte) {
  return colbyte ^ ((row & 7) << 4);
}

__device__ __forceinline__ u32x4 ldsfrag(const char* p, int row, int colbyte, int stride) {
  return *(const u32x4*)(p + row * stride + swz(row, colbyte));
}
__device__ __forceinline__ void lds_st16(char* p, int row, int colbyte, int stride, u16 v) {
  *(u16*)(p + row * stride + swz(row, colbyte)) = v;
}
__device__ __forceinline__ u32x4 gfrag(const u16* p) {
  return *(const u32x4*)p;
}

// ---------- weight prep: f32 -> f16 (contiguous qw|kvw|pw) + head scales ----------
__global__ void wca_prep(const float* __restrict__ qw, const float* __restrict__ kvw,
                         const float* __restrict__ pw, const float* __restrict__ ls,
                         u16* __restrict__ wh, float* __restrict__ scales) {
  int t = blockIdx.x * 256 + threadIdx.x;   // 0..16383, one float4 each
  int e = t * 4;
  const float* src;
  int off;
  if (e < 16384)      { src = qw;  off = e; }
  else if (e < 49152) { src = kvw; off = e - 16384; }
  else                { src = pw;  off = e - 49152; }
  float4 v = *(const float4*)(src + off);
  ushort4 o = { f2h(v.x), f2h(v.y), f2h(v.z), f2h(v.w) };
  *(ushort4*)(wh + e) = o;
  if (t < HEADS) scales[t] = __expf(fminf(ls[t], MAX_LOG_SCALE));
}

// ---------- main kernel: one window per block, 4 waves ----------
__global__ void __launch_bounds__(256) wca_kernel(
    const float* __restrict__ x1, const float* __restrict__ x2,
    const float* __restrict__ qb, const float* __restrict__ vb,
    const float* __restrict__ pb, const u16* __restrict__ wh,
    const float* __restrict__ scales, float* __restrict__ out) {
  __shared__ char smem[LDS_BYTES];
  const int b = blockIdx.x;
  const int tid = threadIdx.x;
  const int wv = tid >> 6;          // wave 0..3 (= head in phase 2)
  const int lane = tid & 63;
  const int lr = lane & 15;         // row/col within 16-tile
  const int lg = lane >> 4;         // k-group / row-group
  const u16* qw  = wh;              // 128x128
  const u16* kvw = wh + 16384;      // 256x128
  const u16* pw  = wh + 49152;      // 128x128

  // ---- phase 0: load x1,x2 -> f16 LDS (swizzled row-major [64][128]) ----
  {
    const float4* p1 = (const float4*)(x1 + (size_t)b * 8192);
    const float4* p2 = (const float4*)(x2 + (size_t)b * 8192);
#pragma unroll
    for (int i = 0; i < 8; ++i) {
      int idx4 = i * 256 + tid;
      float4 a = p1[idx4];
      float4 c = p2[idx4];
      int e = idx4 * 4;
      int row = e >> 7;
      int colb = (e & 127) * 2;
      ushort4 pa = { f2h(a.x), f2h(a.y), f2h(a.z), f2h(a.w) };
      ushort4 pc = { f2h(c.x), f2h(c.y), f2h(c.z), f2h(c.w) };
      *(ushort4*)(smem + LDS_X1 + row * 256 + swz(row, colb)) = pa;
      *(ushort4*)(smem + LDS_X2 + row * 256 + swz(row, colb)) = pc;
    }
  }
  __syncthreads();

  // ---- phase 1: projections. wave strip rows r0..r0+15 for q/k; vT rows 32wv..+32 ----
  const int r0 = wv * 16;
  u32x4 ax1[4], ax2[4];
#pragma unroll
  for (int kc = 0; kc < 4; ++kc) {
    ax1[kc] = ldsfrag(smem + LDS_X1, r0 + lr, kc * 64 + lg * 16, 256);
    ax2[kc] = ldsfrag(smem + LDS_X2, r0 + lr, kc * 64 + lg * 16, 256);
  }
  // q (from x1/qw) and k (from x2/kvw rows 0:128), fused L2 norm per head
#pragma unroll
  for (int h = 0; h < 4; ++h) {
#pragma unroll
    for (int which = 0; which < 2; ++which) {
      const u16* W = which ? kvw : qw;
      f32x4 a0 = {0.f, 0.f, 0.f, 0.f}, a1 = {0.f, 0.f, 0.f, 0.f};
#pragma unroll
      for (int kc = 0; kc < 4; ++kc) {
        u32x4 b0 = gfrag(W + (h * 32 + lr) * 128 + kc * 32 + lg * 8);
        u32x4 b1 = gfrag(W + (h * 32 + 16 + lr) * 128 + kc * 32 + lg * 8);
        u32x4 a = which ? ax2[kc] : ax1[kc];
        mfma16(a0, a, b0);
        mfma16(a1, a, b1);
      }
      if (!which) {
        float b0 = qb[h * 32 + lr], b1 = qb[h * 32 + 16 + lr];
#pragma unroll
        for (int i = 0; i < 4; ++i) { a0[i] += b0; a1[i] += b1; }
      }
      float s[4];
#pragma unroll
      for (int i = 0; i < 4; ++i) s[i] = a0[i] * a0[i] + a1[i] * a1[i];
#pragma unroll
      for (int m = 1; m < 16; m <<= 1)
#pragma unroll
        for (int i = 0; i < 4; ++i) s[i] += __shfl_xor(s[i], m, 64);
      char* dst = smem + (which ? LDS_K : LDS_Q);
#pragma unroll
      for (int i = 0; i < 4; ++i) {
        float r = 1.0f / fmaxf(sqrtf(s[i]), 1e-12f);
        int row = r0 + lg * 4 + i;
        lds_st16(dst, row, (h * 32 + lr) * 2, 256, f2h(a0[i] * r));
        lds_st16(dst, row, (h * 32 + 16 + lr) * 2, 256, f2h(a1[i] * r));
      }
    }
  }
  // vT(j,n) = sum_k kvw[128+j][k] * x2[n][k] + vb[j], rows j in [32wv, 32wv+32)
  {
    u32x4 akv[2][4];
#pragma unroll
    for (int jt = 0; jt < 2; ++jt)
#pragma unroll
      for (int kc = 0; kc < 4; ++kc)
        akv[jt][kc] = gfrag(kvw + (128 + wv * 32 + jt * 16 + lr) * 128 + kc * 32 + lg * 8);
    float vbias[2][4];
#pragma unroll
    for (int jt = 0; jt < 2; ++jt)
#pragma unroll
      for (int i = 0; i < 4; ++i)
        vbias[jt][i] = vb[wv * 32 + jt * 16 + lg * 4 + i];
#pragma unroll
    for (int nt = 0; nt < 4; ++nt) {
      u32x4 bx[4];
#pragma unroll
      for (int kc = 0; kc < 4; ++kc)
        bx[kc] = ldsfrag(smem + LDS_X2, nt * 16 + lr, kc * 64 + lg * 16, 256);
      f32x4 acc[2] = {{0.f,0.f,0.f,0.f},{0.f,0.f,0.f,0.f}};
#pragma unroll
      for (int jt = 0; jt < 2; ++jt)
#pragma unroll
        for (int kc = 0; kc < 4; ++kc)
          mfma16(acc[jt], akv[jt][kc], bx[kc]);
#pragma unroll
      for (int jt = 0; jt < 2; ++jt)
#pragma unroll
        for (int i = 0; i < 4; ++i) {
          int row = wv * 32 + jt * 16 + lg * 4 + i;
          lds_st16(smem + LDS_VT, row, (nt * 16 + lr) * 2, 128,
                   f2h(acc[jt][i] + vbias[jt][i]));
        }
    }
  }
  __syncthreads();

  // ---- phase 2: per-wave head. QK^T -> softmax -> P(LDS) -> PV ----
  const float sc = scales[wv];
  f32x4 att[4][4];
  {
    u32x4 aq[4], bk[4];
#pragma unroll
    for (int t = 0; t < 4; ++t) {
      aq[t] = ldsfrag(smem + LDS_Q, t * 16 + lr, wv * 64 + lg * 16, 256);
      bk[t] = ldsfrag(smem + LDS_K, t * 16 + lr, wv * 64 + lg * 16, 256);
    }
#pragma unroll
    for (int nt = 0; nt < 4; ++nt)
#pragma unroll
      for (int mt = 0; mt < 4; ++mt) {
        f32x4 z = {0.f, 0.f, 0.f, 0.f};
        mfma16(z, aq[nt], bk[mt]);
        att[nt][mt] = z;
      }
  }
  // softmax per row (row n = nt*16 + lg*4 + i, cols spread over lr x mt)
  char* Pbase = smem + wv * 8192;   // overlays x1/x2 (dead after phase 1)
#pragma unroll
  for (int nt = 0; nt < 4; ++nt) {
    float mx[4] = {-1e30f, -1e30f, -1e30f, -1e30f};
#pragma unroll
    for (int i = 0; i < 4; ++i)
#pragma unroll
      for (int mt = 0; mt < 4; ++mt) {
        att[nt][mt][i] *= sc;
        mx[i] = fmaxf(mx[i], att[nt][mt][i]);
      }
#pragma unroll
    for (int m = 1; m < 16; m <<= 1)
#pragma unroll
      for (int i = 0; i < 4; ++i) mx[i] = fmaxf(mx[i], __shfl_xor(mx[i], m, 64));
    float sum[4] = {0.f, 0.f, 0.f, 0.f};
#pragma unroll
    for (int i = 0; i < 4; ++i)
#pragma unroll
      for (int mt = 0; mt < 4; ++mt) {
        float p = __expf(att[nt][mt][i] - mx[i]);
        att[nt][mt][i] = p;
        sum[i] += p;
      }
#pragma unroll
    for (int m = 1; m < 16; m <<= 1)
#pragma unroll
      for (int i = 0; i < 4; ++i) sum[i] += __shfl_xor(sum[i], m, 64);
#pragma unroll
    for (int i = 0; i < 4; ++i) {
      float rs = 1.0f / sum[i];
      int row = nt * 16 + lg * 4 + i;
#pragma unroll
      for (int mt = 0; mt < 4; ++mt)
        lds_st16(Pbase, row, (mt * 16 + lr) * 2, 128, f2h(att[nt][mt][i] * rs));
    }
  }
  __syncthreads();   // all QK reads of q/k done; P visible; O may overlay Q

  // PV: o(n,c) = sum_m P(n,m) * vT(32wv+c, m)
  {
    u32x4 ap[4][2], bv[2][2];
#pragma unroll
    for (int nt = 0; nt < 4; ++nt)
#pragma unroll
      for (int kc = 0; kc < 2; ++kc)
        ap[nt][kc] = ldsfrag(Pbase, nt * 16 + lr, kc * 64 + lg * 16, 128);
#pragma unroll
    for (int ct = 0; ct < 2; ++ct)
#pragma unroll
      for (int kc = 0; kc < 2; ++kc)
        bv[ct][kc] = ldsfrag(smem + LDS_VT, wv * 32 + ct * 16 + lr, kc * 64 + lg * 16, 128);
    f32x4 o[4][2];
#pragma unroll
    for (int nt = 0; nt < 4; ++nt)
#pragma unroll
      for (int ct = 0; ct < 2; ++ct) {
        f32x4 z = {0.f, 0.f, 0.f, 0.f};
#pragma unroll
        for (int kc = 0; kc < 2; ++kc) mfma16(z, ap[nt][kc], bv[ct][kc]);
        o[nt][ct] = z;
      }
    // store o (64x128 over heads) into Q region (own head's columns only)
#pragma unroll
    for (int nt = 0; nt < 4; ++nt)
#pragma unroll
      for (int ct = 0; ct < 2; ++ct)
#pragma unroll
        for (int i = 0; i < 4; ++i) {
          int row = nt * 16 + lg * 4 + i;
          lds_st16(smem + LDS_Q, row, (wv * 32 + ct * 16 + lr) * 2, 256, f2h(o[nt][ct][i]));
        }
  }
  __syncthreads();

  // ---- phase 3: out = o @ pw^T + pb, wave strip rows r0..r0+15 ----
  {
    u32x4 ao[4];
#pragma unroll
    for (int kc = 0; kc < 4; ++kc)
      ao[kc] = ldsfrag(smem + LDS_Q, r0 + lr, kc * 64 + lg * 16, 256);
    float* ob = out + (size_t)b * 8192;
#pragma unroll
    for (int jt = 0; jt < 8; ++jt) {
      f32x4 acc = {0.f, 0.f, 0.f, 0.f};
#pragma unroll
      for (int kc = 0; kc < 4; ++kc) {
        u32x4 bp = gfrag(pw + (jt * 16 + lr) * 128 + kc * 32 + lg * 8);
        mfma16(acc, ao[kc], bp);
      }
      float bj = pb[jt * 16 + lr];
#pragma unroll
      for (int i = 0; i < 4; ++i) {
        int row = r0 + lg * 4 + i;
        ob[row * 128 + jt * 16 + lr] = acc[i] + bj;
      }
    }
  }
}

extern "C" void kernel_launch(void* const* d_in, const int* in_sizes, int n_in,
                              void* d_out, int out_size, void* d_ws, size_t ws_size,
                              hipStream_t stream) {
  const float* x1 = (const float*)d_in[0];
  const float* x2 = (const float*)d_in[1];
  const float* qw = (const float*)d_in[2];
  const float* qb = (const float*)d_in[3];
  const float* kvw = (const float*)d_in[4];
  const float* vb = (const float*)d_in[5];
  const float* ls = (const float*)d_in[6];
  const float* pw = (const float*)d_in[7];
  const float* pb = (const float*)d_in[8];
  u16* wh = (u16*)d_ws;                          // 65536 f16 = 128 KB
  float* scales = (float*)((char*)d_ws + 131072); // 4 floats

  wca_prep<<<64, 256, 0, stream>>>(qw, kvw, pw, ls, wh, scales);
  wca_kernel<<<NWIN, 256, 0, stream>>>(x1, x2, qb, vb, pb, wh, scales, (float*)d_out);
}

// Round 3
// 461.253 us; speedup vs baseline: 1.1450x; 1.1450x over previous
//
#include <hip/hip_runtime.h>

typedef float f32x4 __attribute__((ext_vector_type(4)));
typedef unsigned int u32x4 __attribute__((ext_vector_type(4)));
typedef _Float16 f16x8 __attribute__((ext_vector_type(8)));
typedef _Float16 f16x2 __attribute__((ext_vector_type(2)));
typedef unsigned short u16;
typedef unsigned int u32;

// ---- constants ----
#define NWIN 8192
#define MAX_LOG_SCALE 4.605170185988091f  // log(100)

// LDS regions (48 KB total -> 3 blocks/CU):
//   A [0,16K):   X1 -> VT([128][64]) -> O([64][128])
//   B [16K,32K): X2 -> Q([64][128]); P(waves 0,1) overlays after aq/bk loads
//   C [32K,48K): K([64][128]);       P(waves 2,3) overlays after aq/bk loads
#define RA 0
#define RB 16384
#define RC 32768
#define LDS_BYTES 49152

__device__ __forceinline__ void mfma16(f32x4& acc, u32x4 a, u32x4 b) {
  acc = __builtin_amdgcn_mfma_f32_16x16x32_f16(
      __builtin_bit_cast(f16x8, a), __builtin_bit_cast(f16x8, b), acc, 0, 0, 0);
}

__device__ __forceinline__ u16 f2h(float f) {
  return __builtin_bit_cast(u16, (_Float16)f);
}
__device__ __forceinline__ u32 pkh(float x, float y) {  // packed f32->f16 (RTZ)
  return __builtin_bit_cast(u32, __builtin_amdgcn_cvt_pkrtz(x, y));
}

// XOR swizzle: spreads row-major [r][128]f16 (256B rows) / [r][64]f16 (128B rows)
// column reads across banks. 16B-granule bijective within each 8-row stripe.
__device__ __forceinline__ int swz(int row, int colbyte) {
  return colbyte ^ ((row & 7) << 4);
}
__device__ __forceinline__ u32x4 ldsfrag(const char* p, int row, int colbyte, int stride) {
  return *(const u32x4*)(p + row * stride + swz(row, colbyte));
}
__device__ __forceinline__ void lds_st16(char* p, int row, int colbyte, int stride, u16 v) {
  *(u16*)(p + row * stride + swz(row, colbyte)) = v;
}
__device__ __forceinline__ u32x4 gfrag(const u16* p) {
  return *(const u32x4*)p;
}

// ---------- weight prep: f32 -> f16 (contiguous qw|kvw|pw) + head scales ----------
__global__ void wca_prep(const float* __restrict__ qw, const float* __restrict__ kvw,
                         const float* __restrict__ pw, const float* __restrict__ ls,
                         u16* __restrict__ wh, float* __restrict__ scales) {
  int t = blockIdx.x * 256 + threadIdx.x;   // 0..16383, one float4 each
  int e = t * 4;
  const float* src;
  int off;
  if (e < 16384)      { src = qw;  off = e; }
  else if (e < 49152) { src = kvw; off = e - 16384; }
  else                { src = pw;  off = e - 49152; }
  float4 v = *(const float4*)(src + off);
  uint2 o = { pkh(v.x, v.y), pkh(v.z, v.w) };
  *(uint2*)(wh + e) = o;
  if (t < 4) scales[t] = __expf(fminf(ls[t], MAX_LOG_SCALE));
}

// ---------- main kernel: one window per block, 4 waves, 3 blocks/CU ----------
__global__ void __launch_bounds__(256, 3) wca_kernel(
    const float* __restrict__ x1, const float* __restrict__ x2,
    const float* __restrict__ qb, const float* __restrict__ vb,
    const float* __restrict__ pb, const u16* __restrict__ wh,
    const float* __restrict__ scales, float* __restrict__ out) {
  __shared__ char smem[LDS_BYTES];
  const int b = blockIdx.x;
  const int tid = threadIdx.x;
  const int wv = tid >> 6;          // wave 0..3 (= head in phase 2)
  const int lane = tid & 63;
  const int lr = lane & 15;         // row/col within 16-tile
  const int lg = lane >> 4;         // k-group / row-group
  const u16* qw  = wh;              // 128x128
  const u16* kvw = wh + 16384;      // 256x128
  const u16* pw  = wh + 49152;      // 128x128

  // ---- phase 0: load x1,x2 -> f16 LDS (all 16 loads hoisted for MLP) ----
  {
    const float4* p1 = (const float4*)(x1 + (size_t)b * 8192);
    const float4* p2 = (const float4*)(x2 + (size_t)b * 8192);
    float4 a[8], c[8];
#pragma unroll
    for (int i = 0; i < 8; ++i) { a[i] = p1[i * 256 + tid]; c[i] = p2[i * 256 + tid]; }
#pragma unroll
    for (int i = 0; i < 8; ++i) {
      int e = (i * 256 + tid) * 4;
      int row = e >> 7;
      int colb = (e & 127) * 2;
      uint2 pa = { pkh(a[i].x, a[i].y), pkh(a[i].z, a[i].w) };
      uint2 pc = { pkh(c[i].x, c[i].y), pkh(c[i].z, c[i].w) };
      *(uint2*)(smem + RA + row * 256 + swz(row, colb)) = pa;
      *(uint2*)(smem + RB + row * 256 + swz(row, colb)) = pc;
    }
  }
  __syncthreads();  // (1) X1,X2 visible

  // ---- phase 1a: own-strip x1/x2 fragments -> registers ----
  const int r0 = wv * 16;
  u32x4 ax1[4], ax2[4];
#pragma unroll
  for (int kc = 0; kc < 4; ++kc) {
    ax1[kc] = ldsfrag(smem + RA, r0 + lr, kc * 64 + lg * 16, 256);
    ax2[kc] = ldsfrag(smem + RB, r0 + lr, kc * 64 + lg * 16, 256);
  }
  __syncthreads();  // (2) X1 region (A) now dead -> VT may overlay

  // ---- phase 1b: vT(j,n) = sum_k kvw[128+j][k]*x2[n][k] + vb[j], j in [32wv,32wv+32) ----
  {
    u32x4 akv[2][4];
#pragma unroll
    for (int jt = 0; jt < 2; ++jt)
#pragma unroll
      for (int kc = 0; kc < 4; ++kc)
        akv[jt][kc] = gfrag(kvw + (128 + wv * 32 + jt * 16 + lr) * 128 + kc * 32 + lg * 8);
    float vbias[2][4];
#pragma unroll
    for (int jt = 0; jt < 2; ++jt)
#pragma unroll
      for (int i = 0; i < 4; ++i)
        vbias[jt][i] = vb[wv * 32 + jt * 16 + lg * 4 + i];
#pragma unroll
    for (int nt = 0; nt < 4; ++nt) {
      u32x4 bx[4];
#pragma unroll
      for (int kc = 0; kc < 4; ++kc)
        bx[kc] = ldsfrag(smem + RB, nt * 16 + lr, kc * 64 + lg * 16, 256);
      f32x4 acc[2] = {{0.f,0.f,0.f,0.f},{0.f,0.f,0.f,0.f}};
#pragma unroll
      for (int jt = 0; jt < 2; ++jt)
#pragma unroll
        for (int kc = 0; kc < 4; ++kc)
          mfma16(acc[jt], akv[jt][kc], bx[kc]);
#pragma unroll
      for (int jt = 0; jt < 2; ++jt)
#pragma unroll
        for (int i = 0; i < 4; ++i) {
          int row = wv * 32 + jt * 16 + lg * 4 + i;
          lds_st16(smem + RA, row, (nt * 16 + lr) * 2, 128,
                   f2h(acc[jt][i] + vbias[jt][i]));
        }
    }
  }
  __syncthreads();  // (3) X2 region (B) now dead -> Q may overlay

  // ---- phase 1c: q (x1@qw^T+qb) -> B, k (x2@kvw[0:128]^T) -> C, fused L2 norm ----
#pragma unroll
  for (int h = 0; h < 4; ++h) {
#pragma unroll
    for (int which = 0; which < 2; ++which) {
      const u16* W = which ? kvw : qw;
      f32x4 a0 = {0.f, 0.f, 0.f, 0.f}, a1 = {0.f, 0.f, 0.f, 0.f};
#pragma unroll
      for (int kc = 0; kc < 4; ++kc) {
        u32x4 b0 = gfrag(W + (h * 32 + lr) * 128 + kc * 32 + lg * 8);
        u32x4 b1 = gfrag(W + (h * 32 + 16 + lr) * 128 + kc * 32 + lg * 8);
        u32x4 a = which ? ax2[kc] : ax1[kc];
        mfma16(a0, a, b0);
        mfma16(a1, a, b1);
      }
      if (!which) {
        float b0 = qb[h * 32 + lr], b1 = qb[h * 32 + 16 + lr];
#pragma unroll
        for (int i = 0; i < 4; ++i) { a0[i] += b0; a1[i] += b1; }
      }
      float s[4];
#pragma unroll
      for (int i = 0; i < 4; ++i) s[i] = a0[i] * a0[i] + a1[i] * a1[i];
#pragma unroll
      for (int m = 1; m < 16; m <<= 1)
#pragma unroll
        for (int i = 0; i < 4; ++i) s[i] += __shfl_xor(s[i], m, 64);
      char* dst = smem + (which ? RC : RB);
#pragma unroll
      for (int i = 0; i < 4; ++i) {
        float r = 1.0f / fmaxf(sqrtf(s[i]), 1e-12f);
        int row = r0 + lg * 4 + i;
        lds_st16(dst, row, (h * 32 + lr) * 2, 256, f2h(a0[i] * r));
        lds_st16(dst, row, (h * 32 + 16 + lr) * 2, 256, f2h(a1[i] * r));
      }
    }
  }
  __syncthreads();  // (4) Q,K visible

  // ---- phase 2: per-wave head. Load all LDS operands, then one barrier ----
  const float sc = scales[wv];
  u32x4 aq[4], bk[4], bv[2][2];
#pragma unroll
  for (int t = 0; t < 4; ++t) {
    aq[t] = ldsfrag(smem + RB, t * 16 + lr, wv * 64 + lg * 16, 256);
    bk[t] = ldsfrag(smem + RC, t * 16 + lr, wv * 64 + lg * 16, 256);
  }
#pragma unroll
  for (int ct = 0; ct < 2; ++ct)
#pragma unroll
    for (int kc = 0; kc < 2; ++kc)
      bv[ct][kc] = ldsfrag(smem + RA, wv * 32 + ct * 16 + lr, kc * 64 + lg * 16, 128);
  __syncthreads();  // (5) Q/K/VT reads done by all -> P may overlay B+C, O may overlay A

  f32x4 att[4][4];
#pragma unroll
  for (int nt = 0; nt < 4; ++nt)
#pragma unroll
    for (int mt = 0; mt < 4; ++mt) {
      f32x4 z = {0.f, 0.f, 0.f, 0.f};
      mfma16(z, aq[nt], bk[mt]);
      att[nt][mt] = z;
    }
  // softmax per row; logits = sc*cos <= sc, so use fixed max bound sc (no reduce)
  char* Pbase = smem + RB + wv * 8192;  // wv0,1 -> B halves; wv2,3 -> C halves
#pragma unroll
  for (int nt = 0; nt < 4; ++nt) {
    float sum[4] = {0.f, 0.f, 0.f, 0.f};
#pragma unroll
    for (int i = 0; i < 4; ++i)
#pragma unroll
      for (int mt = 0; mt < 4; ++mt) {
        float p = __expf(fmaf(att[nt][mt][i], sc, -sc));
        att[nt][mt][i] = p;
        sum[i] += p;
      }
#pragma unroll
    for (int m = 1; m < 16; m <<= 1)
#pragma unroll
      for (int i = 0; i < 4; ++i) sum[i] += __shfl_xor(sum[i], m, 64);
#pragma unroll
    for (int i = 0; i < 4; ++i) {
      float rs = 1.0f / sum[i];
      int row = nt * 16 + lg * 4 + i;
#pragma unroll
      for (int mt = 0; mt < 4; ++mt)
        lds_st16(Pbase, row, (mt * 16 + lr) * 2, 128, f2h(att[nt][mt][i] * rs));
    }
  }

  // PV: o(n,c) = sum_m P(n,m) * vT(32wv+c, m)   (P is wave-private; no barrier)
  {
    u32x4 ap[4][2];
#pragma unroll
    for (int nt = 0; nt < 4; ++nt)
#pragma unroll
      for (int kc = 0; kc < 2; ++kc)
        ap[nt][kc] = ldsfrag(Pbase, nt * 16 + lr, kc * 64 + lg * 16, 128);
    f32x4 o[4][2];
#pragma unroll
    for (int nt = 0; nt < 4; ++nt)
#pragma unroll
      for (int ct = 0; ct < 2; ++ct) {
        f32x4 z = {0.f, 0.f, 0.f, 0.f};
#pragma unroll
        for (int kc = 0; kc < 2; ++kc) mfma16(z, ap[nt][kc], bv[ct][kc]);
        o[nt][ct] = z;
      }
    // store o (64 rows x own head's 32 cols) into A (VT dead: bv loaded pre-barrier 5)
#pragma unroll
    for (int nt = 0; nt < 4; ++nt)
#pragma unroll
      for (int ct = 0; ct < 2; ++ct)
#pragma unroll
        for (int i = 0; i < 4; ++i) {
          int row = nt * 16 + lg * 4 + i;
          lds_st16(smem + RA, row, (wv * 32 + ct * 16 + lr) * 2, 256, f2h(o[nt][ct][i]));
        }
  }
  __syncthreads();  // (6) O visible

  // ---- phase 3: out = o @ pw^T + pb, wave strip rows r0..r0+15 ----
  {
    u32x4 ao[4];
#pragma unroll
    for (int kc = 0; kc < 4; ++kc)
      ao[kc] = ldsfrag(smem + RA, r0 + lr, kc * 64 + lg * 16, 256);
    float* ob = out + (size_t)b * 8192;
#pragma unroll
    for (int jt = 0; jt < 8; ++jt) {
      f32x4 acc = {0.f, 0.f, 0.f, 0.f};
#pragma unroll
      for (int kc = 0; kc < 4; ++kc) {
        u32x4 bp = gfrag(pw + (jt * 16 + lr) * 128 + kc * 32 + lg * 8);
        mfma16(acc, ao[kc], bp);
      }
      float bj = pb[jt * 16 + lr];
#pragma unroll
      for (int i = 0; i < 4; ++i) {
        int row = r0 + lg * 4 + i;
        ob[row * 128 + jt * 16 + lr] = acc[i] + bj;
      }
    }
  }
}

extern "C" void kernel_launch(void* const* d_in, const int* in_sizes, int n_in,
                              void* d_out, int out_size, void* d_ws, size_t ws_size,
                              hipStream_t stream) {
  const float* x1 = (const float*)d_in[0];
  const float* x2 = (const float*)d_in[1];
  const float* qw = (const float*)d_in[2];
  const float* qb = (const float*)d_in[3];
  const float* kvw = (const float*)d_in[4];
  const float* vb = (const float*)d_in[5];
  const float* ls = (const float*)d_in[6];
  const float* pw = (const float*)d_in[7];
  const float* pb = (const float*)d_in[8];
  u16* wh = (u16*)d_ws;                           // 65536 f16 = 128 KB
  float* scales = (float*)((char*)d_ws + 131072); // 4 floats

  wca_prep<<<64, 256, 0, stream>>>(qw, kvw, pw, ls, wh, scales);
  wca_kernel<<<NWIN, 256, 0, stream>>>(x1, x2, qb, vb, pb, wh, scales, (float*)d_out);
}